// Round 3
// baseline (1665.600 us; speedup 1.0000x reference)
//
#include <hip/hip_runtime.h>

#define TPB 256
#define TPF 1024
constexpr int LS = 264600;          // 6.0 s * 44100 Hz
constexpr int N1 = 525;             // LS = N1 * N2
constexpr int N2 = 504;
constexpr int ROWS = 32;            // S*C = 16*2
constexpr int M_FFT = 16384;        // Bluestein conv length >= 2*NL-1 (NL<=8192)
constexpr float TWO_PI_F = 6.28318530717958647692f;
constexpr float PI_F     = 3.14159265358979323846f;

__device__ __forceinline__ float2 cmul(float2 a, float2 b) {
    return make_float2(a.x * b.x - a.y * b.y, a.x * b.y + a.y * b.x);
}
// XOR-swizzled LDS index for the 128x128 array: row-wise, column-wise and
// linear wave accesses all conflict-free (16 distinct bank-pairs / 16 lanes).
__device__ __forceinline__ int sidx(int hi, int lo) {
    return (hi << 7) + (lo ^ (hi & 15));
}

// ---------------------------------------------------------------------------
// In-register FFT networks (DIF, natural in, bit-reversed out).
// Constant tables + full unroll -> twiddles fold to immediates.
// ---------------------------------------------------------------------------
template<bool INV>
__device__ __forceinline__ void fft16r(float2 v[16]) {
    const float C16[8] = {1.f, 0.92387953251128674f, 0.70710678118654752f, 0.38268343236508977f,
                          0.f, -0.38268343236508977f, -0.70710678118654752f, -0.92387953251128674f};
    const float S16[8] = {0.f, 0.38268343236508977f, 0.70710678118654752f, 0.92387953251128674f,
                          1.f, 0.92387953251128674f, 0.70710678118654752f, 0.38268343236508977f};
    const float sg = INV ? 1.f : -1.f;
    #pragma unroll
    for (int ls = 3; ls >= 0; --ls) {
        const int span = 1 << ls;
        #pragma unroll
        for (int g = 0; g < 16; g += 2 * span) {
            #pragma unroll
            for (int j = 0; j < span; ++j) {
                const int u = g + j, w = u + span;
                float2 a = v[u], b = v[w];
                float2 d = make_float2(a.x - b.x, a.y - b.y);
                v[u] = make_float2(a.x + b.x, a.y + b.y);
                const int ti = j << (3 - ls);
                v[w] = make_float2(d.x * C16[ti] - d.y * sg * S16[ti],
                                   d.x * sg * S16[ti] + d.y * C16[ti]);
            }
        }
    }
}

template<bool INV>
__device__ __forceinline__ void fft8r(float2 v[8]) {
    const float C8[4] = {1.f, 0.70710678118654752f, 0.f, -0.70710678118654752f};
    const float S8[4] = {0.f, 0.70710678118654752f, 1.f, 0.70710678118654752f};
    const float sg = INV ? 1.f : -1.f;
    #pragma unroll
    for (int ls = 2; ls >= 0; --ls) {
        const int span = 1 << ls;
        #pragma unroll
        for (int g = 0; g < 8; g += 2 * span) {
            #pragma unroll
            for (int j = 0; j < span; ++j) {
                const int u = g + j, w = u + span;
                float2 a = v[u], b = v[w];
                float2 d = make_float2(a.x - b.x, a.y - b.y);
                v[u] = make_float2(a.x + b.x, a.y + b.y);
                const int ti = j << (2 - ls);
                v[w] = make_float2(d.x * C8[ti] - d.y * sg * S8[ti],
                                   d.x * sg * S8[ti] + d.y * C8[ti]);
            }
        }
    }
}

// ---------------------------------------------------------------------------
// K0: per-bin scan of G for nonzero head/tail block sizes (exact-0 padding).
// ---------------------------------------------------------------------------
__global__ void k0_scan(const float* __restrict__ G, int NL, int* __restrict__ hnh) {
    const int j = blockIdx.x;
    __shared__ int s_first, s_last;
    if (threadIdx.x == 0) { s_first = NL; s_last = -1; }
    __syncthreads();
    const float* Gj = G + (size_t)j * NL;
    for (int m = threadIdx.x; m < NL; m += blockDim.x) {
        if (Gj[m] == 0.0f) {
            atomicMin(&s_first, m);
            atomicMax(&s_last, m);
        }
    }
    __syncthreads();
    if (threadIdx.x == 0) {
        int h  = s_first;
        int nh = (s_last >= 0) ? (NL - 1 - s_last) : 0;
        hnh[2 * j]     = h;
        hnh[2 * j + 1] = nh;
    }
}

// ---------------------------------------------------------------------------
// K1: 525-point DFT per (n2, r), split 525 = 25 x 21 (Cooley-Tukey in LDS).
// ---------------------------------------------------------------------------
__global__ __launch_bounds__(TPB) void k1_dft525(const float* __restrict__ x,
                                                 float2* __restrict__ A) {
    const int n2 = blockIdx.x;
    const int r  = blockIdx.y;
    __shared__ float  xs[N1];
    __shared__ float2 ys[N1];
    __shared__ float2 w25[25];
    __shared__ float2 w21[21];
    const float* xr = x + (size_t)r * LS + n2;
    for (int t = threadIdx.x; t < N1; t += TPB) {
        xs[t] = xr[(size_t)t * N2];
    }
    if (threadIdx.x < 25) {
        float a = -TWO_PI_F * (float)threadIdx.x / 25.0f;
        float s, c; sincosf(a, &s, &c);
        w25[threadIdx.x] = make_float2(c, s);
    } else if (threadIdx.x >= 32 && threadIdx.x < 53) {
        int k = threadIdx.x - 32;
        float a = -TWO_PI_F * (float)k / 21.0f;
        float s, c; sincosf(a, &s, &c);
        w21[k] = make_float2(c, s);
    }
    __syncthreads();
    for (int i = threadIdx.x; i < N1; i += TPB) {
        int alpha = i % 25, b = i / 25;
        float re = 0.f, im = 0.f;
        int iw = 0, it = b;
        #pragma unroll
        for (int a = 0; a < 25; ++a) {
            float  v = xs[it];
            float2 w = w25[iw];
            re = fmaf(v, w.x, re);
            im = fmaf(v, w.y, im);
            it += 21;
            iw += alpha; if (iw >= 25) iw -= 25;
        }
        float ang = -TWO_PI_F * (float)(b * alpha) / (float)N1;
        float s, c; sincosf(ang, &s, &c);
        ys[i] = make_float2(re * c - im * s, re * s + im * c);
    }
    __syncthreads();
    for (int k = threadIdx.x; k < N1; k += TPB) {
        int alpha = k % 25, beta = k / 25;
        float re = 0.f, im = 0.f;
        int iw = 0, iy = alpha;
        #pragma unroll
        for (int b = 0; b < 21; ++b) {
            float2 v = ys[iy];
            float2 w = w21[iw];
            re = fmaf(v.x, w.x, re); re = fmaf(-v.y, w.y, re);
            im = fmaf(v.x, w.y, im); im = fmaf( v.y, w.x, im);
            iy += 25;
            iw += beta; if (iw >= 21) iw -= 21;
        }
        float ang = -TWO_PI_F * (float)(k * n2) / (float)LS;
        float s, c; sincosf(ang, &s, &c);
        A[((size_t)r * N1 + k) * N2 + n2] = make_float2(re * c - im * s, re * s + im * c);
    }
}

// ---------------------------------------------------------------------------
// K2: 504-point DFT per (k1, r), split 504 = 21 x 24 (Cooley-Tukey in LDS).
// ---------------------------------------------------------------------------
__global__ __launch_bounds__(TPB) void k2_dft504(float2* __restrict__ A) {
    const int k1 = blockIdx.x;
    const int r  = blockIdx.y;
    __shared__ float2 as[N2];
    __shared__ float2 ys[N2];
    __shared__ float2 w21[21];
    __shared__ float2 w24[24];
    float2* row = A + ((size_t)r * N1 + k1) * N2;
    for (int t = threadIdx.x; t < N2; t += TPB) as[t] = row[t];
    if (threadIdx.x < 21) {
        float a = -TWO_PI_F * (float)threadIdx.x / 21.0f;
        float s, c; sincosf(a, &s, &c);
        w21[threadIdx.x] = make_float2(c, s);
    } else if (threadIdx.x >= 32 && threadIdx.x < 56) {
        int k = threadIdx.x - 32;
        float a = -TWO_PI_F * (float)k / 24.0f;
        float s, c; sincosf(a, &s, &c);
        w24[k] = make_float2(c, s);
    }
    __syncthreads();
    for (int i = threadIdx.x; i < N2; i += TPB) {
        int alpha = i % 21, b = i / 21;
        float re = 0.f, im = 0.f;
        int iw = 0, it = b;
        #pragma unroll
        for (int a = 0; a < 21; ++a) {
            float2 v = as[it];
            float2 w = w21[iw];
            re = fmaf(v.x, w.x, re); re = fmaf(-v.y, w.y, re);
            im = fmaf(v.x, w.y, im); im = fmaf( v.y, w.x, im);
            it += 24;
            iw += alpha; if (iw >= 21) iw -= 21;
        }
        float ang = -TWO_PI_F * (float)(b * alpha) / (float)N2;
        float s, c; sincosf(ang, &s, &c);
        ys[i] = make_float2(re * c - im * s, re * s + im * c);
    }
    __syncthreads();
    for (int k = threadIdx.x; k < N2; k += TPB) {
        int alpha = k % 21, beta = k / 21;
        float re = 0.f, im = 0.f;
        int iw = 0, iy = alpha;
        #pragma unroll
        for (int b = 0; b < 24; ++b) {
            float2 v = ys[iy];
            float2 w = w24[iw];
            re = fmaf(v.x, w.x, re); re = fmaf(-v.y, w.y, re);
            im = fmaf(v.x, w.y, im); im = fmaf( v.y, w.x, im);
            iy += 21;
            iw += beta; if (iw >= 24) iw -= 24;
        }
        row[k] = make_float2(re, im);
    }
}

// ---------------------------------------------------------------------------
// K_SETUP: chirp tables + 128-entry W_128 twiddle table.
// ---------------------------------------------------------------------------
__global__ void k_setup(float2* __restrict__ kc, float2* __restrict__ bchirp,
                        float2* __restrict__ twg, int NL) {
    int t = blockIdx.x * blockDim.x + threadIdx.x;
    long long twoNL = 2LL * NL;
    if (t < M_FFT) {
        long long d = 0; bool act = false;
        if (t < NL)              { d = t;        act = true; }
        else if (t > M_FFT - NL) { d = t - M_FFT; act = true; }
        float2 v = make_float2(0.f, 0.f);
        if (act) {
            long long ph = (d * d) % twoNL;
            float th = -PI_F * (float)ph / (float)NL;
            float s, c; sincosf(th, &s, &c);
            v = make_float2(c, s);
        }
        kc[t] = v;
    } else {
        int n = t - M_FFT;
        if (n < NL) {
            long long ph = ((long long)n * n) % twoNL;
            float th = PI_F * (float)ph / (float)NL;
            float s, c; sincosf(th, &s, &c);
            bchirp[n] = make_float2(c, s);
        } else if (n < NL + 128) {
            int q = n - NL;
            float th = -TWO_PI_F * (float)q / 128.0f;
            float s, c; sincosf(th, &s, &c);
            twg[q] = make_float2(c, s);
        }
    }
}

// ---------------------------------------------------------------------------
// Shared forward core: everything after the stage-1 column registers are
// loaded. v[n1] must hold input x[(8*n1+n2)*128 + lo].
// On exit: mp(hi=r, lo=s) = X[r + 128*s], with a trailing barrier done.
// ---------------------------------------------------------------------------
__device__ __forceinline__ void fwd_after_load(float2* __restrict__ mp,
        const float2* __restrict__ twg, float2 v[16], int lo, int n2) {
    const int RV4[16] = {0,8,4,12,2,10,6,14,1,9,5,13,3,11,7,15};
    const int RV3[8]  = {0,4,2,6,1,5,3,7};
    // ----- columns stage 1: FFT16 over n1, twiddle W_128^{n2*k1} -----
    fft16r<false>(v);
    #pragma unroll
    for (int p = 0; p < 16; ++p) {
        const int k1 = RV4[p];
        mp[sidx(8 * k1 + n2, lo)] = cmul(v[p], twg[n2 * k1]);
    }
    __syncthreads();
    // ----- columns stage 2: FFT8 over n2, fold mid twiddle W_M^{r*lo} -----
    {
        float2 u0[8], u1[8];
        const int q = n2;
        #pragma unroll
        for (int m = 0; m < 8; ++m) u0[m] = mp[sidx(8 * q + m, lo)];
        #pragma unroll
        for (int m = 0; m < 8; ++m) u1[m] = mp[sidx(8 * (q + 8) + m, lo)];
        __syncthreads();
        fft8r<false>(u0);
        fft8r<false>(u1);
        #pragma unroll
        for (int p = 0; p < 8; ++p) {
            const int k2 = RV3[p];
            {
                const int rr = q + 16 * k2;
                float th = -TWO_PI_F * (float)(rr * lo) / (float)M_FFT;
                float s, c; sincosf(th, &s, &c);
                mp[sidx(rr, lo)] = cmul(u0[p], make_float2(c, s));
            }
            {
                const int rr = q + 8 + 16 * k2;
                float th = -TWO_PI_F * (float)(rr * lo) / (float)M_FFT;
                float s, c; sincosf(th, &s, &c);
                mp[sidx(rr, lo)] = cmul(u1[p], make_float2(c, s));
            }
        }
    }
    __syncthreads();
    // ----- rows stage 1: FFT16 over n1 (along lo), twiddle W_128^{n2*k1} -----
    const int hi = lo;      // thread now owns row hi
    #pragma unroll
    for (int n1 = 0; n1 < 16; ++n1) v[n1] = mp[sidx(hi, 8 * n1 + n2)];
    fft16r<false>(v);
    #pragma unroll
    for (int p = 0; p < 16; ++p) {
        const int k1 = RV4[p];
        mp[sidx(hi, 8 * k1 + n2)] = cmul(v[p], twg[n2 * k1]);
    }
    __syncthreads();
    // ----- rows stage 2: FFT8 over n2 (no extra twiddle) -----
    {
        float2 u0[8], u1[8];
        const int q = n2;
        #pragma unroll
        for (int m = 0; m < 8; ++m) u0[m] = mp[sidx(hi, 8 * q + m)];
        #pragma unroll
        for (int m = 0; m < 8; ++m) u1[m] = mp[sidx(hi, 8 * (q + 8) + m)];
        __syncthreads();
        fft8r<false>(u0);
        fft8r<false>(u1);
        #pragma unroll
        for (int p = 0; p < 8; ++p) {
            const int k2 = RV3[p];
            mp[sidx(hi, q + 16 * k2)]     = u0[p];
            mp[sidx(hi, q + 8 + 16 * k2)] = u1[p];
        }
    }
    __syncthreads();
}

// ---------------------------------------------------------------------------
// K_KF: one block. KFt[s*128 + r] = FFT16k(kc)[r + 128*s]  (transposed store
// so k_fused's inverse-row loads are coalesced).
// ---------------------------------------------------------------------------
__global__ __launch_bounds__(TPF, 4) void k_kf(const float2* __restrict__ kc,
        const float2* __restrict__ twg, float2* __restrict__ KFt) {
    extern __shared__ float2 mp[];
    const int tid = threadIdx.x;
    const int lo = tid & 127, n2 = tid >> 7;
    float2 v[16];
    #pragma unroll
    for (int n1 = 0; n1 < 16; ++n1)
        v[n1] = kc[(size_t)(8 * n1 + n2) * 128 + lo];
    fwd_after_load(mp, twg, v, lo, n2);
    for (int i = tid; i < M_FFT; i += TPF) {
        int hh = i >> 7, ll = i & 127;
        KFt[(size_t)ll * 128 + hh] = mp[sidx(hh, ll)];
    }
}

// ---------------------------------------------------------------------------
// K_FUSED: one transform per block; gather -> fwd -> xKF -> inv -> out,
// with register-resident 8x16 FFT-128 stages (7 LDS read + 7 write sweeps).
// ---------------------------------------------------------------------------
__global__ __launch_bounds__(TPF, 4) void k_fused(const float* __restrict__ Gm,
        const int* __restrict__ idxp, const float2* __restrict__ A,
        const int* __restrict__ hnh, const float2* __restrict__ bchirp,
        const float2* __restrict__ KFt, const float2* __restrict__ twg,
        float2* __restrict__ out, int NB, int NL) {
    extern __shared__ float2 mp[];
    const int tid = threadIdx.x;
    const int lo = tid & 127, n2 = tid >> 7;
    const int vg = blockIdx.x;
    const int rr_ = vg / NB, jb = vg % NB;
    const int h = hnh[2 * jb], nh = hnh[2 * jb + 1];
    const int tail0 = NL - nh;
    const float* Gj = Gm + (size_t)jb * NL;
    const int*   ij = idxp + (size_t)jb * NL;
    const float2* Ar = A + (size_t)rr_ * LS;
    const int RV4[16] = {0,8,4,12,2,10,6,14,1,9,5,13,3,11,7,15};
    const int RV3[8]  = {0,4,2,6,1,5,3,7};

    // ===== forward (gather fused into stage-1 loads) =====
    float2 v[16];
    #pragma unroll
    for (int n1 = 0; n1 < 16; ++n1) {
        const int i = (8 * n1 + n2) * 128 + lo;
        float2 val = make_float2(0.f, 0.f);
        if (i < h || (i >= tail0 && i < NL)) {
            int k = ij[i];
            float2 f = Ar[(size_t)(k % N1) * N2 + (k / N1)];
            float  g = Gj[i];
            val = cmul(make_float2(f.x * g, f.y * g), bchirp[i]);
        }
        v[n1] = val;
    }
    fwd_after_load(mp, twg, v, lo, n2);
    // mp(r, s) = X[r + 128*s]

    const int hi = lo;   // row index for the inverse-row stages
    // ===== inverse rows stage 1: xKF^T at load, IFFT16 over n1 =====
    #pragma unroll
    for (int n1 = 0; n1 < 16; ++n1) {
        const int s = 8 * n1 + n2;
        v[n1] = cmul(mp[sidx(hi, s)], KFt[(size_t)s * 128 + hi]);
    }
    fft16r<true>(v);
    #pragma unroll
    for (int p = 0; p < 16; ++p) {
        const int k1 = RV4[p];
        float2 t = twg[n2 * k1]; t.y = -t.y;
        mp[sidx(hi, 8 * k1 + n2)] = cmul(v[p], t);
    }
    __syncthreads();
    // ===== inverse rows stage 2: IFFT8, fold inv mid twiddle e^{+2pi b*hi/M} =====
    {
        float2 u0[8], u1[8];
        const int q = n2;
        #pragma unroll
        for (int m = 0; m < 8; ++m) u0[m] = mp[sidx(hi, 8 * q + m)];
        #pragma unroll
        for (int m = 0; m < 8; ++m) u1[m] = mp[sidx(hi, 8 * (q + 8) + m)];
        __syncthreads();
        fft8r<true>(u0);
        fft8r<true>(u1);
        #pragma unroll
        for (int p = 0; p < 8; ++p) {
            const int k2 = RV3[p];
            {
                const int b = q + 16 * k2;
                float th = TWO_PI_F * (float)(b * hi) / (float)M_FFT;
                float s, c; sincosf(th, &s, &c);
                mp[sidx(hi, b)] = cmul(u0[p], make_float2(c, s));
            }
            {
                const int b = q + 8 + 16 * k2;
                float th = TWO_PI_F * (float)(b * hi) / (float)M_FFT;
                float s, c; sincosf(th, &s, &c);
                mp[sidx(hi, b)] = cmul(u1[p], make_float2(c, s));
            }
        }
    }
    __syncthreads();
    // ===== inverse cols stage 1: IFFT16 over n1 (along hi) =====
    #pragma unroll
    for (int n1 = 0; n1 < 16; ++n1) v[n1] = mp[sidx(8 * n1 + n2, lo)];
    fft16r<true>(v);
    #pragma unroll
    for (int p = 0; p < 16; ++p) {
        const int k1 = RV4[p];
        float2 t = twg[n2 * k1]; t.y = -t.y;
        mp[sidx(8 * k1 + n2, lo)] = cmul(v[p], t);
    }
    __syncthreads();
    // ===== inverse cols stage 2: IFFT8 -> y[128*a + lo] -> global out =====
    {
        float2 u0[8], u1[8];
        const int q = n2;
        #pragma unroll
        for (int m = 0; m < 8; ++m) u0[m] = mp[sidx(8 * q + m, lo)];
        #pragma unroll
        for (int m = 0; m < 8; ++m) u1[m] = mp[sidx(8 * (q + 8) + m, lo)];
        fft8r<true>(u0);
        fft8r<true>(u1);
        const float sc = 100.0f / ((float)NL * (float)M_FFT);
        float2* outv = out + (size_t)vg * NL;
        #pragma unroll
        for (int p = 0; p < 8; ++p) {
            const int k2 = RV3[p];
            {
                const int a = q + 16 * k2;
                const int n = 128 * a + lo;
                if (n < NL) {
                    float2 y = cmul(u0[p], bchirp[n]);
                    outv[n] = make_float2(y.x * sc, y.y * sc);
                }
            }
            {
                const int a = q + 8 + 16 * k2;
                const int n = 128 * a + lo;
                if (n < NL) {
                    float2 y = cmul(u1[p], bchirp[n]);
                    outv[n] = make_float2(y.x * sc, y.y * sc);
                }
            }
        }
    }
}

// ---------------------------------------------------------------------------
// Legacy direct zoom-IDFT — fallback if NL too large or ws too small.
// ---------------------------------------------------------------------------
__global__ __launch_bounds__(TPB) void k3_idft(const float* __restrict__ G,
                                               const int*  __restrict__ idxp,
                                               const float2* __restrict__ FT,
                                               const int*  __restrict__ hnh,
                                               float2* __restrict__ out,
                                               int NB, int NL) {
    extern __shared__ float2 cls[];
    const int j = blockIdx.x;
    const int r = blockIdx.y;
    const int h  = hnh[2 * j];
    const int nh = hnh[2 * j + 1];
    const int Lg = h + nh;
    const float* Gj = G    + (size_t)j * NL;
    const int*   ij = idxp + (size_t)j * NL;

    for (int t = threadIdx.x; t < Lg; t += TPB) {
        int m = (t < h) ? t : (NL - nh + (t - h));
        int k = ij[m];
        float2 f = FT[((size_t)r * N1 + (k % N1)) * N2 + (k / N1)];
        float  g = Gj[m];
        cls[t] = make_float2(f.x * g, f.y * g);
    }
    __syncthreads();

    const float scale = 100.0f / (float)NL;
    const float w0 = TWO_PI_F / (float)NL;
    float2* outr = out + ((size_t)r * NB + j) * NL;

    for (int n_base = 0; n_base < NL; n_base += 4 * TPB) {
        int   n[4];
        float are[4], aim[4], twr[4], twi[4], str[4], sti[4];
        #pragma unroll
        for (int u = 0; u < 4; ++u) {
            n[u] = n_base + u * TPB + (int)threadIdx.x;
            are[u] = 0.f; aim[u] = 0.f;
            float s, c; sincosf(w0 * (float)(n[u] % NL), &s, &c);
            str[u] = c; sti[u] = s;
            twr[u] = 1.f; twi[u] = 0.f;
        }
        for (int t = 0; t < h; ++t) {
            if ((t & 255) == 0) {
                #pragma unroll
                for (int u = 0; u < 4; ++u) {
                    int mm = (int)(((long long)t * (long long)n[u]) % NL);
                    float s, c; sincosf(w0 * (float)mm, &s, &c);
                    twr[u] = c; twi[u] = s;
                }
            }
            float2 cv = cls[t];
            #pragma unroll
            for (int u = 0; u < 4; ++u) {
                are[u] = fmaf(cv.x, twr[u], are[u]);
                are[u] = fmaf(-cv.y, twi[u], are[u]);
                aim[u] = fmaf(cv.x, twi[u], aim[u]);
                aim[u] = fmaf(cv.y, twr[u], aim[u]);
                float nr = twr[u] * str[u] - twi[u] * sti[u];
                float ni = twr[u] * sti[u] + twi[u] * str[u];
                twr[u] = nr; twi[u] = ni;
            }
        }
        const int m0 = NL - nh;
        for (int t = 0; t < nh; ++t) {
            if ((t & 255) == 0) {
                #pragma unroll
                for (int u = 0; u < 4; ++u) {
                    int mm = (int)(((long long)(m0 + t) * (long long)n[u]) % NL);
                    float s, c; sincosf(w0 * (float)mm, &s, &c);
                    twr[u] = c; twi[u] = s;
                }
            }
            float2 cv = cls[h + t];
            #pragma unroll
            for (int u = 0; u < 4; ++u) {
                are[u] = fmaf(cv.x, twr[u], are[u]);
                are[u] = fmaf(-cv.y, twi[u], are[u]);
                aim[u] = fmaf(cv.x, twi[u], aim[u]);
                aim[u] = fmaf(cv.y, twr[u], aim[u]);
                float nr = twr[u] * str[u] - twi[u] * sti[u];
                float ni = twr[u] * sti[u] + twi[u] * str[u];
                twr[u] = nr; twi[u] = ni;
            }
        }
        #pragma unroll
        for (int u = 0; u < 4; ++u) {
            if (n[u] < NL) outr[n[u]] = make_float2(are[u] * scale, aim[u] * scale);
        }
    }
}

// ---------------------------------------------------------------------------
static inline size_t align256(size_t x) { return (x + 255) & ~(size_t)255; }

extern "C" void kernel_launch(void* const* d_in, const int* in_sizes, int n_in,
                              void* d_out, int out_size, void* d_ws, size_t ws_size,
                              hipStream_t stream) {
    const float* x   = (const float*)d_in[0];
    const float* Gm  = (const float*)d_in[1];
    const int*   idx = (const int*)d_in[2];
    float2*      out = (float2*)d_out;

    const int p  = in_sizes[1];
    const int NB = (p % 114 == 0) ? 114 : 115;
    const int NL = p / NB;
    const int B  = NB * ROWS;

    // ws layout: hnh | bchirp | twg(128) | kc | KFt | A
    size_t hnh_off    = 0;
    size_t bchirp_off = align256(hnh_off + 2048);
    size_t twg_off    = align256(bchirp_off + (size_t)NL * 8);
    size_t kc_off     = align256(twg_off + 128 * 8);
    size_t kft_off    = align256(kc_off + (size_t)M_FFT * 8);
    size_t A_off      = align256(kft_off + (size_t)M_FFT * 8);
    size_t need       = A_off + (size_t)ROWS * LS * 8;

    int*    hnh    = (int*)((char*)d_ws + hnh_off);
    float2* bchirp = (float2*)((char*)d_ws + bchirp_off);
    float2* twg    = (float2*)((char*)d_ws + twg_off);
    float2* kc     = (float2*)((char*)d_ws + kc_off);
    float2* KFt    = (float2*)((char*)d_ws + kft_off);
    float2* A      = (float2*)((char*)d_ws + A_off);

    k0_scan<<<dim3(NB), TPB, 0, stream>>>(Gm, NL, hnh);
    k1_dft525<<<dim3(N2, ROWS), TPB, 0, stream>>>(x, A);
    k2_dft504<<<dim3(N1, ROWS), TPB, 0, stream>>>(A);

    const bool fused_ok = (2 * NL - 1 <= M_FFT) && (need <= ws_size);
    if (fused_ok) {
        (void)hipFuncSetAttribute((const void*)k_fused,
                                  hipFuncAttributeMaxDynamicSharedMemorySize,
                                  M_FFT * (int)sizeof(float2));
        (void)hipFuncSetAttribute((const void*)k_kf,
                                  hipFuncAttributeMaxDynamicSharedMemorySize,
                                  M_FFT * (int)sizeof(float2));
        int setup_blocks = (M_FFT + NL + 128 + TPB - 1) / TPB;
        k_setup<<<dim3(setup_blocks), TPB, 0, stream>>>(kc, bchirp, twg, NL);
        k_kf<<<dim3(1), TPF, (size_t)M_FFT * sizeof(float2), stream>>>(kc, twg, KFt);
        k_fused<<<dim3(B), TPF, (size_t)M_FFT * sizeof(float2), stream>>>(
            Gm, idx, A, hnh, bchirp, KFt, twg, out, NB, NL);
    } else {
        k3_idft<<<dim3(NB, ROWS), TPB, (size_t)NL * sizeof(float2), stream>>>(
            Gm, idx, A, hnh, out, NB, NL);
    }
}

// Round 4
// 1625.233 us; speedup vs baseline: 1.0248x; 1.0248x over previous
//
#include <hip/hip_runtime.h>

#define TPB 256
#define TPF 1024
constexpr int LS = 264600;          // 6.0 s * 44100 Hz
constexpr int N1 = 525;             // LS = N1 * N2
constexpr int N2 = 504;
constexpr int ROWS = 32;            // S*C = 16*2
constexpr int M_FFT = 16384;        // Bluestein conv length >= 2*NL-1 (NL<=8192)
constexpr float TWO_PI_F = 6.28318530717958647692f;
constexpr float PI_F     = 3.14159265358979323846f;

__device__ __forceinline__ float2 cmul(float2 a, float2 b) {
    return make_float2(a.x * b.x - a.y * b.y, a.x * b.y + a.y * b.x);
}
// XOR-swizzled LDS index for the 128x128 array: row-wise, column-wise and
// linear wave accesses all conflict-free (16 distinct bank-pairs / 16 lanes).
__device__ __forceinline__ int sidx(int hi, int lo) {
    return (hi << 7) + (lo ^ (hi & 15));
}

// ---------------------------------------------------------------------------
// Register FFT networks on NAMED scalars (no arrays -> guaranteed VGPRs).
// DIF, natural in, bit-reversed out. Twiddles are compile-time immediates.
// ---------------------------------------------------------------------------
#define BFLY(u, w, C, S) do {                       \
    float dx_ = (u).x - (w).x, dy_ = (u).y - (w).y; \
    (u).x += (w).x; (u).y += (w).y;                 \
    (w).x = dx_ * (C) - dy_ * (S);                  \
    (w).y = dx_ * (S) + dy_ * (C);                  \
} while (0)

template<bool INV>
__device__ __forceinline__ void fft16s(float2 &a0, float2 &a1, float2 &a2, float2 &a3,
                                       float2 &a4, float2 &a5, float2 &a6, float2 &a7,
                                       float2 &a8, float2 &a9, float2 &a10, float2 &a11,
                                       float2 &a12, float2 &a13, float2 &a14, float2 &a15) {
    constexpr float c1 = 0.92387953251128674f;
    constexpr float s1 = 0.38268343236508977f;
    constexpr float r2 = 0.70710678118654752f;
    const float sg = INV ? 1.f : -1.f;
    // span 8 (ti = j)
    BFLY(a0, a8,  1.f, 0.f);
    BFLY(a1, a9,  c1,  sg * s1);
    BFLY(a2, a10, r2,  sg * r2);
    BFLY(a3, a11, s1,  sg * c1);
    BFLY(a4, a12, 0.f, sg * 1.f);
    BFLY(a5, a13, -s1, sg * c1);
    BFLY(a6, a14, -r2, sg * r2);
    BFLY(a7, a15, -c1, sg * s1);
    // span 4 (ti = 2j)
    BFLY(a0, a4,  1.f, 0.f);
    BFLY(a1, a5,  r2,  sg * r2);
    BFLY(a2, a6,  0.f, sg * 1.f);
    BFLY(a3, a7,  -r2, sg * r2);
    BFLY(a8, a12, 1.f, 0.f);
    BFLY(a9, a13, r2,  sg * r2);
    BFLY(a10, a14, 0.f, sg * 1.f);
    BFLY(a11, a15, -r2, sg * r2);
    // span 2 (ti = 4j)
    BFLY(a0, a2,  1.f, 0.f);
    BFLY(a1, a3,  0.f, sg * 1.f);
    BFLY(a4, a6,  1.f, 0.f);
    BFLY(a5, a7,  0.f, sg * 1.f);
    BFLY(a8, a10, 1.f, 0.f);
    BFLY(a9, a11, 0.f, sg * 1.f);
    BFLY(a12, a14, 1.f, 0.f);
    BFLY(a13, a15, 0.f, sg * 1.f);
    // span 1
    BFLY(a0, a1,  1.f, 0.f);
    BFLY(a2, a3,  1.f, 0.f);
    BFLY(a4, a5,  1.f, 0.f);
    BFLY(a6, a7,  1.f, 0.f);
    BFLY(a8, a9,  1.f, 0.f);
    BFLY(a10, a11, 1.f, 0.f);
    BFLY(a12, a13, 1.f, 0.f);
    BFLY(a14, a15, 1.f, 0.f);
}

template<bool INV>
__device__ __forceinline__ void fft8s(float2 &b0, float2 &b1, float2 &b2, float2 &b3,
                                      float2 &b4, float2 &b5, float2 &b6, float2 &b7) {
    constexpr float r2 = 0.70710678118654752f;
    const float sg = INV ? 1.f : -1.f;
    BFLY(b0, b4, 1.f, 0.f);
    BFLY(b1, b5, r2,  sg * r2);
    BFLY(b2, b6, 0.f, sg * 1.f);
    BFLY(b3, b7, -r2, sg * r2);
    BFLY(b0, b2, 1.f, 0.f);
    BFLY(b1, b3, 0.f, sg * 1.f);
    BFLY(b4, b6, 1.f, 0.f);
    BFLY(b5, b7, 0.f, sg * 1.f);
    BFLY(b0, b1, 1.f, 0.f);
    BFLY(b2, b3, 1.f, 0.f);
    BFLY(b4, b5, 1.f, 0.f);
    BFLY(b6, b7, 1.f, 0.f);
}

#define CTW(w) make_float2((w).x, -(w).y)

// Mid-twiddle stores (forward / inverse), use mp, lo/hi from scope.
#define STW_FWD(var, rr) do {                                              \
    float th_ = -TWO_PI_F * (float)((rr) * lo) / (float)M_FFT;             \
    float s_, c_; sincosf(th_, &s_, &c_);                                  \
    mp[sidx((rr), lo)] = cmul((var), make_float2(c_, s_));                 \
} while (0)

#define STW_INV(var, bc) do {                                              \
    float th_ = TWO_PI_F * (float)((bc) * hi) / (float)M_FFT;              \
    float s_, c_; sincosf(th_, &s_, &c_);                                  \
    mp[sidx(hi, (bc))] = cmul((var), make_float2(c_, s_));                 \
} while (0)

// ---------------------------------------------------------------------------
// Forward four-step core on named scalars. On entry a0..a15 hold
// x[1024*n1 + 128*n2 + lo] for n1=0..15. On exit mp(hi=r, lo=s) = X[r+128*s],
// trailing barrier done.
// ---------------------------------------------------------------------------
__device__ __forceinline__ void fwd_core(float2* __restrict__ mp,
        const float2* __restrict__ twg, const int lo, const int n2,
        float2 &a0, float2 &a1, float2 &a2, float2 &a3,
        float2 &a4, float2 &a5, float2 &a6, float2 &a7,
        float2 &a8, float2 &a9, float2 &a10, float2 &a11,
        float2 &a12, float2 &a13, float2 &a14, float2 &a15) {
    // ----- cols stage 1: FFT16 over n1, twiddle W_128^{n2*k1}, bitrev k1 -----
    fft16s<false>(a0, a1, a2, a3, a4, a5, a6, a7, a8, a9, a10, a11, a12, a13, a14, a15);
    mp[sidx(n2,       lo)] = a0;
    mp[sidx(64 + n2,  lo)] = cmul(a1,  twg[n2 * 8]);
    mp[sidx(32 + n2,  lo)] = cmul(a2,  twg[n2 * 4]);
    mp[sidx(96 + n2,  lo)] = cmul(a3,  twg[n2 * 12]);
    mp[sidx(16 + n2,  lo)] = cmul(a4,  twg[n2 * 2]);
    mp[sidx(80 + n2,  lo)] = cmul(a5,  twg[n2 * 10]);
    mp[sidx(48 + n2,  lo)] = cmul(a6,  twg[n2 * 6]);
    mp[sidx(112 + n2, lo)] = cmul(a7,  twg[n2 * 14]);
    mp[sidx(8 + n2,   lo)] = cmul(a8,  twg[n2 * 1]);
    mp[sidx(72 + n2,  lo)] = cmul(a9,  twg[n2 * 9]);
    mp[sidx(40 + n2,  lo)] = cmul(a10, twg[n2 * 5]);
    mp[sidx(104 + n2, lo)] = cmul(a11, twg[n2 * 13]);
    mp[sidx(24 + n2,  lo)] = cmul(a12, twg[n2 * 3]);
    mp[sidx(88 + n2,  lo)] = cmul(a13, twg[n2 * 11]);
    mp[sidx(56 + n2,  lo)] = cmul(a14, twg[n2 * 7]);
    mp[sidx(120 + n2, lo)] = cmul(a15, twg[n2 * 15]);
    __syncthreads();
    // ----- cols stage 2: FFT8 over n2, fold mid twiddle W_M^{r*lo} -----
    {
        float2 b0 = mp[sidx(8 * n2 + 0, lo)];
        float2 b1 = mp[sidx(8 * n2 + 1, lo)];
        float2 b2 = mp[sidx(8 * n2 + 2, lo)];
        float2 b3 = mp[sidx(8 * n2 + 3, lo)];
        float2 b4 = mp[sidx(8 * n2 + 4, lo)];
        float2 b5 = mp[sidx(8 * n2 + 5, lo)];
        float2 b6 = mp[sidx(8 * n2 + 6, lo)];
        float2 b7 = mp[sidx(8 * n2 + 7, lo)];
        float2 c0 = mp[sidx(8 * n2 + 64, lo)];
        float2 c1 = mp[sidx(8 * n2 + 65, lo)];
        float2 c2 = mp[sidx(8 * n2 + 66, lo)];
        float2 c3 = mp[sidx(8 * n2 + 67, lo)];
        float2 c4 = mp[sidx(8 * n2 + 68, lo)];
        float2 c5 = mp[sidx(8 * n2 + 69, lo)];
        float2 c6 = mp[sidx(8 * n2 + 70, lo)];
        float2 c7 = mp[sidx(8 * n2 + 71, lo)];
        __syncthreads();
        fft8s<false>(b0, b1, b2, b3, b4, b5, b6, b7);
        fft8s<false>(c0, c1, c2, c3, c4, c5, c6, c7);
        STW_FWD(b0, n2 + 0);  STW_FWD(b1, n2 + 64);
        STW_FWD(b2, n2 + 32); STW_FWD(b3, n2 + 96);
        STW_FWD(b4, n2 + 16); STW_FWD(b5, n2 + 80);
        STW_FWD(b6, n2 + 48); STW_FWD(b7, n2 + 112);
        STW_FWD(c0, n2 + 8);  STW_FWD(c1, n2 + 72);
        STW_FWD(c2, n2 + 40); STW_FWD(c3, n2 + 104);
        STW_FWD(c4, n2 + 24); STW_FWD(c5, n2 + 88);
        STW_FWD(c6, n2 + 56); STW_FWD(c7, n2 + 120);
    }
    __syncthreads();
    // ----- rows stage 1: FFT16 along lo, twiddle W_128^{n2*k1} -----
    const int hi = lo;
    a0  = mp[sidx(hi, n2)];
    a1  = mp[sidx(hi, 8 + n2)];
    a2  = mp[sidx(hi, 16 + n2)];
    a3  = mp[sidx(hi, 24 + n2)];
    a4  = mp[sidx(hi, 32 + n2)];
    a5  = mp[sidx(hi, 40 + n2)];
    a6  = mp[sidx(hi, 48 + n2)];
    a7  = mp[sidx(hi, 56 + n2)];
    a8  = mp[sidx(hi, 64 + n2)];
    a9  = mp[sidx(hi, 72 + n2)];
    a10 = mp[sidx(hi, 80 + n2)];
    a11 = mp[sidx(hi, 88 + n2)];
    a12 = mp[sidx(hi, 96 + n2)];
    a13 = mp[sidx(hi, 104 + n2)];
    a14 = mp[sidx(hi, 112 + n2)];
    a15 = mp[sidx(hi, 120 + n2)];
    fft16s<false>(a0, a1, a2, a3, a4, a5, a6, a7, a8, a9, a10, a11, a12, a13, a14, a15);
    mp[sidx(hi, n2)]       = a0;
    mp[sidx(hi, 64 + n2)]  = cmul(a1,  twg[n2 * 8]);
    mp[sidx(hi, 32 + n2)]  = cmul(a2,  twg[n2 * 4]);
    mp[sidx(hi, 96 + n2)]  = cmul(a3,  twg[n2 * 12]);
    mp[sidx(hi, 16 + n2)]  = cmul(a4,  twg[n2 * 2]);
    mp[sidx(hi, 80 + n2)]  = cmul(a5,  twg[n2 * 10]);
    mp[sidx(hi, 48 + n2)]  = cmul(a6,  twg[n2 * 6]);
    mp[sidx(hi, 112 + n2)] = cmul(a7,  twg[n2 * 14]);
    mp[sidx(hi, 8 + n2)]   = cmul(a8,  twg[n2 * 1]);
    mp[sidx(hi, 72 + n2)]  = cmul(a9,  twg[n2 * 9]);
    mp[sidx(hi, 40 + n2)]  = cmul(a10, twg[n2 * 5]);
    mp[sidx(hi, 104 + n2)] = cmul(a11, twg[n2 * 13]);
    mp[sidx(hi, 24 + n2)]  = cmul(a12, twg[n2 * 3]);
    mp[sidx(hi, 88 + n2)]  = cmul(a13, twg[n2 * 11]);
    mp[sidx(hi, 56 + n2)]  = cmul(a14, twg[n2 * 7]);
    mp[sidx(hi, 120 + n2)] = cmul(a15, twg[n2 * 15]);
    __syncthreads();
    // ----- rows stage 2: FFT8 over n2 (no extra twiddle) -----
    {
        float2 b0 = mp[sidx(hi, 8 * n2 + 0)];
        float2 b1 = mp[sidx(hi, 8 * n2 + 1)];
        float2 b2 = mp[sidx(hi, 8 * n2 + 2)];
        float2 b3 = mp[sidx(hi, 8 * n2 + 3)];
        float2 b4 = mp[sidx(hi, 8 * n2 + 4)];
        float2 b5 = mp[sidx(hi, 8 * n2 + 5)];
        float2 b6 = mp[sidx(hi, 8 * n2 + 6)];
        float2 b7 = mp[sidx(hi, 8 * n2 + 7)];
        float2 c0 = mp[sidx(hi, 8 * n2 + 64)];
        float2 c1 = mp[sidx(hi, 8 * n2 + 65)];
        float2 c2 = mp[sidx(hi, 8 * n2 + 66)];
        float2 c3 = mp[sidx(hi, 8 * n2 + 67)];
        float2 c4 = mp[sidx(hi, 8 * n2 + 68)];
        float2 c5 = mp[sidx(hi, 8 * n2 + 69)];
        float2 c6 = mp[sidx(hi, 8 * n2 + 70)];
        float2 c7 = mp[sidx(hi, 8 * n2 + 71)];
        __syncthreads();
        fft8s<false>(b0, b1, b2, b3, b4, b5, b6, b7);
        fft8s<false>(c0, c1, c2, c3, c4, c5, c6, c7);
        mp[sidx(hi, n2 + 0)]   = b0;
        mp[sidx(hi, n2 + 64)]  = b1;
        mp[sidx(hi, n2 + 32)]  = b2;
        mp[sidx(hi, n2 + 96)]  = b3;
        mp[sidx(hi, n2 + 16)]  = b4;
        mp[sidx(hi, n2 + 80)]  = b5;
        mp[sidx(hi, n2 + 48)]  = b6;
        mp[sidx(hi, n2 + 112)] = b7;
        mp[sidx(hi, n2 + 8)]   = c0;
        mp[sidx(hi, n2 + 72)]  = c1;
        mp[sidx(hi, n2 + 40)]  = c2;
        mp[sidx(hi, n2 + 104)] = c3;
        mp[sidx(hi, n2 + 24)]  = c4;
        mp[sidx(hi, n2 + 88)]  = c5;
        mp[sidx(hi, n2 + 56)]  = c6;
        mp[sidx(hi, n2 + 120)] = c7;
    }
    __syncthreads();
}

// ---------------------------------------------------------------------------
// K0: per-bin scan of G for nonzero head/tail block sizes (exact-0 padding).
// ---------------------------------------------------------------------------
__global__ void k0_scan(const float* __restrict__ G, int NL, int* __restrict__ hnh) {
    const int j = blockIdx.x;
    __shared__ int s_first, s_last;
    if (threadIdx.x == 0) { s_first = NL; s_last = -1; }
    __syncthreads();
    const float* Gj = G + (size_t)j * NL;
    for (int m = threadIdx.x; m < NL; m += blockDim.x) {
        if (Gj[m] == 0.0f) {
            atomicMin(&s_first, m);
            atomicMax(&s_last, m);
        }
    }
    __syncthreads();
    if (threadIdx.x == 0) {
        int h  = s_first;
        int nh = (s_last >= 0) ? (NL - 1 - s_last) : 0;
        hnh[2 * j]     = h;
        hnh[2 * j + 1] = nh;
    }
}

// ---------------------------------------------------------------------------
// K1: 525-point DFT per (n2, r), split 525 = 25 x 21 (Cooley-Tukey in LDS).
// ---------------------------------------------------------------------------
__global__ __launch_bounds__(TPB) void k1_dft525(const float* __restrict__ x,
                                                 float2* __restrict__ A) {
    const int n2 = blockIdx.x;
    const int r  = blockIdx.y;
    __shared__ float  xs[N1];
    __shared__ float2 ys[N1];
    __shared__ float2 w25[25];
    __shared__ float2 w21[21];
    const float* xr = x + (size_t)r * LS + n2;
    for (int t = threadIdx.x; t < N1; t += TPB) {
        xs[t] = xr[(size_t)t * N2];
    }
    if (threadIdx.x < 25) {
        float a = -TWO_PI_F * (float)threadIdx.x / 25.0f;
        float s, c; sincosf(a, &s, &c);
        w25[threadIdx.x] = make_float2(c, s);
    } else if (threadIdx.x >= 32 && threadIdx.x < 53) {
        int k = threadIdx.x - 32;
        float a = -TWO_PI_F * (float)k / 21.0f;
        float s, c; sincosf(a, &s, &c);
        w21[k] = make_float2(c, s);
    }
    __syncthreads();
    for (int i = threadIdx.x; i < N1; i += TPB) {
        int alpha = i % 25, b = i / 25;
        float re = 0.f, im = 0.f;
        int iw = 0, it = b;
        #pragma unroll
        for (int a = 0; a < 25; ++a) {
            float  v = xs[it];
            float2 w = w25[iw];
            re = fmaf(v, w.x, re);
            im = fmaf(v, w.y, im);
            it += 21;
            iw += alpha; if (iw >= 25) iw -= 25;
        }
        float ang = -TWO_PI_F * (float)(b * alpha) / (float)N1;
        float s, c; sincosf(ang, &s, &c);
        ys[i] = make_float2(re * c - im * s, re * s + im * c);
    }
    __syncthreads();
    for (int k = threadIdx.x; k < N1; k += TPB) {
        int alpha = k % 25, beta = k / 25;
        float re = 0.f, im = 0.f;
        int iw = 0, iy = alpha;
        #pragma unroll
        for (int b = 0; b < 21; ++b) {
            float2 v = ys[iy];
            float2 w = w21[iw];
            re = fmaf(v.x, w.x, re); re = fmaf(-v.y, w.y, re);
            im = fmaf(v.x, w.y, im); im = fmaf( v.y, w.x, im);
            iy += 25;
            iw += beta; if (iw >= 21) iw -= 21;
        }
        float ang = -TWO_PI_F * (float)(k * n2) / (float)LS;
        float s, c; sincosf(ang, &s, &c);
        A[((size_t)r * N1 + k) * N2 + n2] = make_float2(re * c - im * s, re * s + im * c);
    }
}

// ---------------------------------------------------------------------------
// K2: 504-point DFT per (k1, r), split 504 = 21 x 24 (Cooley-Tukey in LDS).
// ---------------------------------------------------------------------------
__global__ __launch_bounds__(TPB) void k2_dft504(float2* __restrict__ A) {
    const int k1 = blockIdx.x;
    const int r  = blockIdx.y;
    __shared__ float2 as[N2];
    __shared__ float2 ys[N2];
    __shared__ float2 w21[21];
    __shared__ float2 w24[24];
    float2* row = A + ((size_t)r * N1 + k1) * N2;
    for (int t = threadIdx.x; t < N2; t += TPB) as[t] = row[t];
    if (threadIdx.x < 21) {
        float a = -TWO_PI_F * (float)threadIdx.x / 21.0f;
        float s, c; sincosf(a, &s, &c);
        w21[threadIdx.x] = make_float2(c, s);
    } else if (threadIdx.x >= 32 && threadIdx.x < 56) {
        int k = threadIdx.x - 32;
        float a = -TWO_PI_F * (float)k / 24.0f;
        float s, c; sincosf(a, &s, &c);
        w24[k] = make_float2(c, s);
    }
    __syncthreads();
    for (int i = threadIdx.x; i < N2; i += TPB) {
        int alpha = i % 21, b = i / 21;
        float re = 0.f, im = 0.f;
        int iw = 0, it = b;
        #pragma unroll
        for (int a = 0; a < 21; ++a) {
            float2 v = as[it];
            float2 w = w21[iw];
            re = fmaf(v.x, w.x, re); re = fmaf(-v.y, w.y, re);
            im = fmaf(v.x, w.y, im); im = fmaf( v.y, w.x, im);
            it += 24;
            iw += alpha; if (iw >= 21) iw -= 21;
        }
        float ang = -TWO_PI_F * (float)(b * alpha) / (float)N2;
        float s, c; sincosf(ang, &s, &c);
        ys[i] = make_float2(re * c - im * s, re * s + im * c);
    }
    __syncthreads();
    for (int k = threadIdx.x; k < N2; k += TPB) {
        int alpha = k % 21, beta = k / 21;
        float re = 0.f, im = 0.f;
        int iw = 0, iy = alpha;
        #pragma unroll
        for (int b = 0; b < 24; ++b) {
            float2 v = ys[iy];
            float2 w = w24[iw];
            re = fmaf(v.x, w.x, re); re = fmaf(-v.y, w.y, re);
            im = fmaf(v.x, w.y, im); im = fmaf( v.y, w.x, im);
            iy += 21;
            iw += beta; if (iw >= 24) iw -= 24;
        }
        row[k] = make_float2(re, im);
    }
}

// ---------------------------------------------------------------------------
// K_SETUP: chirp tables + 128-entry W_128 twiddle table.
// ---------------------------------------------------------------------------
__global__ void k_setup(float2* __restrict__ kc, float2* __restrict__ bchirp,
                        float2* __restrict__ twg, int NL) {
    int t = blockIdx.x * blockDim.x + threadIdx.x;
    long long twoNL = 2LL * NL;
    if (t < M_FFT) {
        long long d = 0; bool act = false;
        if (t < NL)              { d = t;        act = true; }
        else if (t > M_FFT - NL) { d = t - M_FFT; act = true; }
        float2 v = make_float2(0.f, 0.f);
        if (act) {
            long long ph = (d * d) % twoNL;
            float th = -PI_F * (float)ph / (float)NL;
            float s, c; sincosf(th, &s, &c);
            v = make_float2(c, s);
        }
        kc[t] = v;
    } else {
        int n = t - M_FFT;
        if (n < NL) {
            long long ph = ((long long)n * n) % twoNL;
            float th = PI_F * (float)ph / (float)NL;
            float s, c; sincosf(th, &s, &c);
            bchirp[n] = make_float2(c, s);
        } else if (n < NL + 128) {
            int q = n - NL;
            float th = -TWO_PI_F * (float)q / 128.0f;
            float s, c; sincosf(th, &s, &c);
            twg[q] = make_float2(c, s);
        }
    }
}

// ---------------------------------------------------------------------------
// K_KF: one block. KFt[s*128 + r] = FFT16k(kc)[r + 128*s]  (transposed store
// so k_fused's inverse-row loads are coalesced).
// ---------------------------------------------------------------------------
__global__ __launch_bounds__(TPF) void k_kf(const float2* __restrict__ kc,
        const float2* __restrict__ twg, float2* __restrict__ KFt) {
    extern __shared__ float2 mp[];
    const int tid = threadIdx.x;
    const int lo = tid & 127, n2 = tid >> 7;
    float2 a0  = kc[tid];
    float2 a1  = kc[1024 + tid];
    float2 a2  = kc[2048 + tid];
    float2 a3  = kc[3072 + tid];
    float2 a4  = kc[4096 + tid];
    float2 a5  = kc[5120 + tid];
    float2 a6  = kc[6144 + tid];
    float2 a7  = kc[7168 + tid];
    float2 a8  = kc[8192 + tid];
    float2 a9  = kc[9216 + tid];
    float2 a10 = kc[10240 + tid];
    float2 a11 = kc[11264 + tid];
    float2 a12 = kc[12288 + tid];
    float2 a13 = kc[13312 + tid];
    float2 a14 = kc[14336 + tid];
    float2 a15 = kc[15360 + tid];
    fwd_core(mp, twg, lo, n2, a0, a1, a2, a3, a4, a5, a6, a7,
             a8, a9, a10, a11, a12, a13, a14, a15);
    for (int i = tid; i < M_FFT; i += TPF) {
        int hh = i >> 7, ll = i & 127;
        KFt[(size_t)ll * 128 + hh] = mp[sidx(hh, ll)];
    }
}

// ---------------------------------------------------------------------------
// K_FUSED: one transform per block; gather -> fwd -> xKF -> inv -> out.
// All FFT state in named scalar registers; LDS only between stages.
// ---------------------------------------------------------------------------
#define GATH(var, I) do {                                                     \
    (var) = make_float2(0.f, 0.f);                                            \
    const int i_ = (I);                                                       \
    if (i_ < h || (i_ >= tail0 && i_ < NL)) {                                 \
        int k_ = ij[i_];                                                      \
        float2 f_ = Ar[(size_t)(k_ % N1) * N2 + (k_ / N1)];                   \
        float  g_ = Gj[i_];                                                   \
        (var) = cmul(make_float2(f_.x * g_, f_.y * g_), bchirp[i_]);          \
    }                                                                         \
} while (0)

#define FINST(var, acol) do {                                                 \
    const int n_ = 128 * (acol) + lo;                                         \
    if (n_ < NL) {                                                            \
        float2 y_ = cmul((var), bchirp[n_]);                                  \
        outv[n_] = make_float2(y_.x * sc, y_.y * sc);                         \
    }                                                                         \
} while (0)

__global__ __launch_bounds__(TPF) void k_fused(const float* __restrict__ Gm,
        const int* __restrict__ idxp, const float2* __restrict__ A,
        const int* __restrict__ hnh, const float2* __restrict__ bchirp,
        const float2* __restrict__ KFt, const float2* __restrict__ twg,
        float2* __restrict__ out, int NB, int NL) {
    extern __shared__ float2 mp[];
    const int tid = threadIdx.x;
    const int lo = tid & 127, n2 = tid >> 7;
    const int vg = blockIdx.x;
    const int rr_ = vg / NB, jb = vg % NB;
    const int h = hnh[2 * jb], nh = hnh[2 * jb + 1];
    const int tail0 = NL - nh;
    const float* Gj = Gm + (size_t)jb * NL;
    const int*   ij = idxp + (size_t)jb * NL;
    const float2* Ar = A + (size_t)rr_ * LS;

    // ===== forward (gather fused into stage-1 loads) =====
    float2 a0, a1, a2, a3, a4, a5, a6, a7, a8, a9, a10, a11, a12, a13, a14, a15;
    GATH(a0, tid);
    GATH(a1, 1024 + tid);
    GATH(a2, 2048 + tid);
    GATH(a3, 3072 + tid);
    GATH(a4, 4096 + tid);
    GATH(a5, 5120 + tid);
    GATH(a6, 6144 + tid);
    GATH(a7, 7168 + tid);
    GATH(a8, 8192 + tid);
    GATH(a9, 9216 + tid);
    GATH(a10, 10240 + tid);
    GATH(a11, 11264 + tid);
    GATH(a12, 12288 + tid);
    GATH(a13, 13312 + tid);
    GATH(a14, 14336 + tid);
    GATH(a15, 15360 + tid);
    fwd_core(mp, twg, lo, n2, a0, a1, a2, a3, a4, a5, a6, a7,
             a8, a9, a10, a11, a12, a13, a14, a15);
    // mp(r, s) = X[r + 128*s]

    const int hi = lo;
    // ===== inverse rows stage 1: xKF^T at load, IFFT16, conj twiddle =====
    a0  = cmul(mp[sidx(hi, n2)],       KFt[(size_t)(n2) * 128 + hi]);
    a1  = cmul(mp[sidx(hi, 8 + n2)],   KFt[(size_t)(8 + n2) * 128 + hi]);
    a2  = cmul(mp[sidx(hi, 16 + n2)],  KFt[(size_t)(16 + n2) * 128 + hi]);
    a3  = cmul(mp[sidx(hi, 24 + n2)],  KFt[(size_t)(24 + n2) * 128 + hi]);
    a4  = cmul(mp[sidx(hi, 32 + n2)],  KFt[(size_t)(32 + n2) * 128 + hi]);
    a5  = cmul(mp[sidx(hi, 40 + n2)],  KFt[(size_t)(40 + n2) * 128 + hi]);
    a6  = cmul(mp[sidx(hi, 48 + n2)],  KFt[(size_t)(48 + n2) * 128 + hi]);
    a7  = cmul(mp[sidx(hi, 56 + n2)],  KFt[(size_t)(56 + n2) * 128 + hi]);
    a8  = cmul(mp[sidx(hi, 64 + n2)],  KFt[(size_t)(64 + n2) * 128 + hi]);
    a9  = cmul(mp[sidx(hi, 72 + n2)],  KFt[(size_t)(72 + n2) * 128 + hi]);
    a10 = cmul(mp[sidx(hi, 80 + n2)],  KFt[(size_t)(80 + n2) * 128 + hi]);
    a11 = cmul(mp[sidx(hi, 88 + n2)],  KFt[(size_t)(88 + n2) * 128 + hi]);
    a12 = cmul(mp[sidx(hi, 96 + n2)],  KFt[(size_t)(96 + n2) * 128 + hi]);
    a13 = cmul(mp[sidx(hi, 104 + n2)], KFt[(size_t)(104 + n2) * 128 + hi]);
    a14 = cmul(mp[sidx(hi, 112 + n2)], KFt[(size_t)(112 + n2) * 128 + hi]);
    a15 = cmul(mp[sidx(hi, 120 + n2)], KFt[(size_t)(120 + n2) * 128 + hi]);
    fft16s<true>(a0, a1, a2, a3, a4, a5, a6, a7, a8, a9, a10, a11, a12, a13, a14, a15);
    mp[sidx(hi, n2)]       = a0;
    mp[sidx(hi, 64 + n2)]  = cmul(a1,  CTW(twg[n2 * 8]));
    mp[sidx(hi, 32 + n2)]  = cmul(a2,  CTW(twg[n2 * 4]));
    mp[sidx(hi, 96 + n2)]  = cmul(a3,  CTW(twg[n2 * 12]));
    mp[sidx(hi, 16 + n2)]  = cmul(a4,  CTW(twg[n2 * 2]));
    mp[sidx(hi, 80 + n2)]  = cmul(a5,  CTW(twg[n2 * 10]));
    mp[sidx(hi, 48 + n2)]  = cmul(a6,  CTW(twg[n2 * 6]));
    mp[sidx(hi, 112 + n2)] = cmul(a7,  CTW(twg[n2 * 14]));
    mp[sidx(hi, 8 + n2)]   = cmul(a8,  CTW(twg[n2 * 1]));
    mp[sidx(hi, 72 + n2)]  = cmul(a9,  CTW(twg[n2 * 9]));
    mp[sidx(hi, 40 + n2)]  = cmul(a10, CTW(twg[n2 * 5]));
    mp[sidx(hi, 104 + n2)] = cmul(a11, CTW(twg[n2 * 13]));
    mp[sidx(hi, 24 + n2)]  = cmul(a12, CTW(twg[n2 * 3]));
    mp[sidx(hi, 88 + n2)]  = cmul(a13, CTW(twg[n2 * 11]));
    mp[sidx(hi, 56 + n2)]  = cmul(a14, CTW(twg[n2 * 7]));
    mp[sidx(hi, 120 + n2)] = cmul(a15, CTW(twg[n2 * 15]));
    __syncthreads();
    // ===== inverse rows stage 2: IFFT8, fold inv mid twiddle =====
    {
        float2 b0 = mp[sidx(hi, 8 * n2 + 0)];
        float2 b1 = mp[sidx(hi, 8 * n2 + 1)];
        float2 b2 = mp[sidx(hi, 8 * n2 + 2)];
        float2 b3 = mp[sidx(hi, 8 * n2 + 3)];
        float2 b4 = mp[sidx(hi, 8 * n2 + 4)];
        float2 b5 = mp[sidx(hi, 8 * n2 + 5)];
        float2 b6 = mp[sidx(hi, 8 * n2 + 6)];
        float2 b7 = mp[sidx(hi, 8 * n2 + 7)];
        float2 c0 = mp[sidx(hi, 8 * n2 + 64)];
        float2 c1 = mp[sidx(hi, 8 * n2 + 65)];
        float2 c2 = mp[sidx(hi, 8 * n2 + 66)];
        float2 c3 = mp[sidx(hi, 8 * n2 + 67)];
        float2 c4 = mp[sidx(hi, 8 * n2 + 68)];
        float2 c5 = mp[sidx(hi, 8 * n2 + 69)];
        float2 c6 = mp[sidx(hi, 8 * n2 + 70)];
        float2 c7 = mp[sidx(hi, 8 * n2 + 71)];
        __syncthreads();
        fft8s<true>(b0, b1, b2, b3, b4, b5, b6, b7);
        fft8s<true>(c0, c1, c2, c3, c4, c5, c6, c7);
        STW_INV(b0, n2 + 0);  STW_INV(b1, n2 + 64);
        STW_INV(b2, n2 + 32); STW_INV(b3, n2 + 96);
        STW_INV(b4, n2 + 16); STW_INV(b5, n2 + 80);
        STW_INV(b6, n2 + 48); STW_INV(b7, n2 + 112);
        STW_INV(c0, n2 + 8);  STW_INV(c1, n2 + 72);
        STW_INV(c2, n2 + 40); STW_INV(c3, n2 + 104);
        STW_INV(c4, n2 + 24); STW_INV(c5, n2 + 88);
        STW_INV(c6, n2 + 56); STW_INV(c7, n2 + 120);
    }
    __syncthreads();
    // ===== inverse cols stage 1: IFFT16 over hi, conj twiddle =====
    a0  = mp[sidx(n2, lo)];
    a1  = mp[sidx(8 + n2, lo)];
    a2  = mp[sidx(16 + n2, lo)];
    a3  = mp[sidx(24 + n2, lo)];
    a4  = mp[sidx(32 + n2, lo)];
    a5  = mp[sidx(40 + n2, lo)];
    a6  = mp[sidx(48 + n2, lo)];
    a7  = mp[sidx(56 + n2, lo)];
    a8  = mp[sidx(64 + n2, lo)];
    a9  = mp[sidx(72 + n2, lo)];
    a10 = mp[sidx(80 + n2, lo)];
    a11 = mp[sidx(88 + n2, lo)];
    a12 = mp[sidx(96 + n2, lo)];
    a13 = mp[sidx(104 + n2, lo)];
    a14 = mp[sidx(112 + n2, lo)];
    a15 = mp[sidx(120 + n2, lo)];
    fft16s<true>(a0, a1, a2, a3, a4, a5, a6, a7, a8, a9, a10, a11, a12, a13, a14, a15);
    mp[sidx(n2, lo)]       = a0;
    mp[sidx(64 + n2, lo)]  = cmul(a1,  CTW(twg[n2 * 8]));
    mp[sidx(32 + n2, lo)]  = cmul(a2,  CTW(twg[n2 * 4]));
    mp[sidx(96 + n2, lo)]  = cmul(a3,  CTW(twg[n2 * 12]));
    mp[sidx(16 + n2, lo)]  = cmul(a4,  CTW(twg[n2 * 2]));
    mp[sidx(80 + n2, lo)]  = cmul(a5,  CTW(twg[n2 * 10]));
    mp[sidx(48 + n2, lo)]  = cmul(a6,  CTW(twg[n2 * 6]));
    mp[sidx(112 + n2, lo)] = cmul(a7,  CTW(twg[n2 * 14]));
    mp[sidx(8 + n2, lo)]   = cmul(a8,  CTW(twg[n2 * 1]));
    mp[sidx(72 + n2, lo)]  = cmul(a9,  CTW(twg[n2 * 9]));
    mp[sidx(40 + n2, lo)]  = cmul(a10, CTW(twg[n2 * 5]));
    mp[sidx(104 + n2, lo)] = cmul(a11, CTW(twg[n2 * 13]));
    mp[sidx(24 + n2, lo)]  = cmul(a12, CTW(twg[n2 * 3]));
    mp[sidx(88 + n2, lo)]  = cmul(a13, CTW(twg[n2 * 11]));
    mp[sidx(56 + n2, lo)]  = cmul(a14, CTW(twg[n2 * 7]));
    mp[sidx(120 + n2, lo)] = cmul(a15, CTW(twg[n2 * 15]));
    __syncthreads();
    // ===== inverse cols stage 2: IFFT8 -> y[128*a + lo] -> global out =====
    {
        float2 b0 = mp[sidx(8 * n2 + 0, lo)];
        float2 b1 = mp[sidx(8 * n2 + 1, lo)];
        float2 b2 = mp[sidx(8 * n2 + 2, lo)];
        float2 b3 = mp[sidx(8 * n2 + 3, lo)];
        float2 b4 = mp[sidx(8 * n2 + 4, lo)];
        float2 b5 = mp[sidx(8 * n2 + 5, lo)];
        float2 b6 = mp[sidx(8 * n2 + 6, lo)];
        float2 b7 = mp[sidx(8 * n2 + 7, lo)];
        float2 c0 = mp[sidx(8 * n2 + 64, lo)];
        float2 c1 = mp[sidx(8 * n2 + 65, lo)];
        float2 c2 = mp[sidx(8 * n2 + 66, lo)];
        float2 c3 = mp[sidx(8 * n2 + 67, lo)];
        float2 c4 = mp[sidx(8 * n2 + 68, lo)];
        float2 c5 = mp[sidx(8 * n2 + 69, lo)];
        float2 c6 = mp[sidx(8 * n2 + 70, lo)];
        float2 c7 = mp[sidx(8 * n2 + 71, lo)];
        fft8s<true>(b0, b1, b2, b3, b4, b5, b6, b7);
        fft8s<true>(c0, c1, c2, c3, c4, c5, c6, c7);
        const float sc = 100.0f / ((float)NL * (float)M_FFT);
        float2* outv = out + (size_t)vg * NL;
        FINST(b0, n2 + 0);  FINST(b1, n2 + 64);
        FINST(b2, n2 + 32); FINST(b3, n2 + 96);
        FINST(b4, n2 + 16); FINST(b5, n2 + 80);
        FINST(b6, n2 + 48); FINST(b7, n2 + 112);
        FINST(c0, n2 + 8);  FINST(c1, n2 + 72);
        FINST(c2, n2 + 40); FINST(c3, n2 + 104);
        FINST(c4, n2 + 24); FINST(c5, n2 + 88);
        FINST(c6, n2 + 56); FINST(c7, n2 + 120);
    }
}

// ---------------------------------------------------------------------------
// Legacy direct zoom-IDFT — fallback if NL too large or ws too small.
// ---------------------------------------------------------------------------
__global__ __launch_bounds__(TPB) void k3_idft(const float* __restrict__ G,
                                               const int*  __restrict__ idxp,
                                               const float2* __restrict__ FT,
                                               const int*  __restrict__ hnh,
                                               float2* __restrict__ out,
                                               int NB, int NL) {
    extern __shared__ float2 cls[];
    const int j = blockIdx.x;
    const int r = blockIdx.y;
    const int h  = hnh[2 * j];
    const int nh = hnh[2 * j + 1];
    const int Lg = h + nh;
    const float* Gj = G    + (size_t)j * NL;
    const int*   ij = idxp + (size_t)j * NL;

    for (int t = threadIdx.x; t < Lg; t += TPB) {
        int m = (t < h) ? t : (NL - nh + (t - h));
        int k = ij[m];
        float2 f = FT[((size_t)r * N1 + (k % N1)) * N2 + (k / N1)];
        float  g = Gj[m];
        cls[t] = make_float2(f.x * g, f.y * g);
    }
    __syncthreads();

    const float scale = 100.0f / (float)NL;
    const float w0 = TWO_PI_F / (float)NL;
    float2* outr = out + ((size_t)r * NB + j) * NL;

    for (int n_base = 0; n_base < NL; n_base += 4 * TPB) {
        int   n[4];
        float are[4], aim[4], twr[4], twi[4], str[4], sti[4];
        #pragma unroll
        for (int u = 0; u < 4; ++u) {
            n[u] = n_base + u * TPB + (int)threadIdx.x;
            are[u] = 0.f; aim[u] = 0.f;
            float s, c; sincosf(w0 * (float)(n[u] % NL), &s, &c);
            str[u] = c; sti[u] = s;
            twr[u] = 1.f; twi[u] = 0.f;
        }
        for (int t = 0; t < h; ++t) {
            if ((t & 255) == 0) {
                #pragma unroll
                for (int u = 0; u < 4; ++u) {
                    int mm = (int)(((long long)t * (long long)n[u]) % NL);
                    float s, c; sincosf(w0 * (float)mm, &s, &c);
                    twr[u] = c; twi[u] = s;
                }
            }
            float2 cv = cls[t];
            #pragma unroll
            for (int u = 0; u < 4; ++u) {
                are[u] = fmaf(cv.x, twr[u], are[u]);
                are[u] = fmaf(-cv.y, twi[u], are[u]);
                aim[u] = fmaf(cv.x, twi[u], aim[u]);
                aim[u] = fmaf(cv.y, twr[u], aim[u]);
                float nr = twr[u] * str[u] - twi[u] * sti[u];
                float ni = twr[u] * sti[u] + twi[u] * str[u];
                twr[u] = nr; twi[u] = ni;
            }
        }
        const int m0 = NL - nh;
        for (int t = 0; t < nh; ++t) {
            if ((t & 255) == 0) {
                #pragma unroll
                for (int u = 0; u < 4; ++u) {
                    int mm = (int)(((long long)(m0 + t) * (long long)n[u]) % NL);
                    float s, c; sincosf(w0 * (float)mm, &s, &c);
                    twr[u] = c; twi[u] = s;
                }
            }
            float2 cv = cls[h + t];
            #pragma unroll
            for (int u = 0; u < 4; ++u) {
                are[u] = fmaf(cv.x, twr[u], are[u]);
                are[u] = fmaf(-cv.y, twi[u], are[u]);
                aim[u] = fmaf(cv.x, twi[u], aim[u]);
                aim[u] = fmaf(cv.y, twr[u], aim[u]);
                float nr = twr[u] * str[u] - twi[u] * sti[u];
                float ni = twr[u] * sti[u] + twi[u] * str[u];
                twr[u] = nr; twi[u] = ni;
            }
        }
        #pragma unroll
        for (int u = 0; u < 4; ++u) {
            if (n[u] < NL) outr[n[u]] = make_float2(are[u] * scale, aim[u] * scale);
        }
    }
}

// ---------------------------------------------------------------------------
static inline size_t align256(size_t x) { return (x + 255) & ~(size_t)255; }

extern "C" void kernel_launch(void* const* d_in, const int* in_sizes, int n_in,
                              void* d_out, int out_size, void* d_ws, size_t ws_size,
                              hipStream_t stream) {
    const float* x   = (const float*)d_in[0];
    const float* Gm  = (const float*)d_in[1];
    const int*   idx = (const int*)d_in[2];
    float2*      out = (float2*)d_out;

    const int p  = in_sizes[1];
    const int NB = (p % 114 == 0) ? 114 : 115;
    const int NL = p / NB;
    const int B  = NB * ROWS;

    // ws layout: hnh | bchirp | twg(128) | kc | KFt | A
    size_t hnh_off    = 0;
    size_t bchirp_off = align256(hnh_off + 2048);
    size_t twg_off    = align256(bchirp_off + (size_t)NL * 8);
    size_t kc_off     = align256(twg_off + 128 * 8);
    size_t kft_off    = align256(kc_off + (size_t)M_FFT * 8);
    size_t A_off      = align256(kft_off + (size_t)M_FFT * 8);
    size_t need       = A_off + (size_t)ROWS * LS * 8;

    int*    hnh    = (int*)((char*)d_ws + hnh_off);
    float2* bchirp = (float2*)((char*)d_ws + bchirp_off);
    float2* twg    = (float2*)((char*)d_ws + twg_off);
    float2* kc     = (float2*)((char*)d_ws + kc_off);
    float2* KFt    = (float2*)((char*)d_ws + kft_off);
    float2* A      = (float2*)((char*)d_ws + A_off);

    k0_scan<<<dim3(NB), TPB, 0, stream>>>(Gm, NL, hnh);
    k1_dft525<<<dim3(N2, ROWS), TPB, 0, stream>>>(x, A);
    k2_dft504<<<dim3(N1, ROWS), TPB, 0, stream>>>(A);

    const bool fused_ok = (2 * NL - 1 <= M_FFT) && (need <= ws_size);
    if (fused_ok) {
        (void)hipFuncSetAttribute((const void*)k_fused,
                                  hipFuncAttributeMaxDynamicSharedMemorySize,
                                  M_FFT * (int)sizeof(float2));
        (void)hipFuncSetAttribute((const void*)k_kf,
                                  hipFuncAttributeMaxDynamicSharedMemorySize,
                                  M_FFT * (int)sizeof(float2));
        int setup_blocks = (M_FFT + NL + 128 + TPB - 1) / TPB;
        k_setup<<<dim3(setup_blocks), TPB, 0, stream>>>(kc, bchirp, twg, NL);
        k_kf<<<dim3(1), TPF, (size_t)M_FFT * sizeof(float2), stream>>>(kc, twg, KFt);
        k_fused<<<dim3(B), TPF, (size_t)M_FFT * sizeof(float2), stream>>>(
            Gm, idx, A, hnh, bchirp, KFt, twg, out, NB, NL);
    } else {
        k3_idft<<<dim3(NB, ROWS), TPB, (size_t)NL * sizeof(float2), stream>>>(
            Gm, idx, A, hnh, out, NB, NL);
    }
}